// Round 15
// baseline (151.304 us; speedup 1.0000x reference)
//
#include <hip/hip_runtime.h>
#include <math.h>

#define S_ 6
#define N_ 10000
#define C_ 128
#define D_ 4
#define H_ 4
#define P_ 8
#define HF_ 28
#define WF_ 50
#define M_ (HF_ * WF_)   // 1400
#define DH_ 32
#define SM_ (S_ * M_)    // 8400
#define QB_ 8            // queries per attn block (256 threads)
// one fp8 value-copy: S*H*M pixels x 32 B = 1,075,200 B
#define ABYTES (S_ * H_ * M_ * 32)

#define NB_V ((SM_ + 31) / 32)   // 263 vproj blocks
#define NB_O ((N_ + 31) / 32)    // 313 OFFL blocks

typedef float floatx2 __attribute__((ext_vector_type(2)));
typedef _Float16 half4h __attribute__((ext_vector_type(4)));

// ---------------------------------------------------------------------------
// Shared GEMM body, K=128, MRx4 micro-tile, k-blocked by 4 with ds_read_b128.
//   MODE 0 (vproj): out = A@B0 + bias0 -> fp8 e4m3, DUAL layout (A/B parity).
//   MODE 1 (OFFL):  out = (A+A2)@[B0|B1] + [bias0|bias1] -> fp32 (Mrows,96).
// ---------------------------------------------------------------------------
template <int NC, int MT, int MR, int MODE>
__device__ __forceinline__ void gemm_body(
    const float* __restrict__ A, const float* __restrict__ A2,
    const float* __restrict__ B0, const float* __restrict__ B1,
    const float* __restrict__ bias0, const float* __restrict__ bias1,
    float* __restrict__ outf, char* __restrict__ out8,
    int Mrows, int m0, int tid, int nthreads, float (*Alds)[132]) {
  constexpr int NTHR = (NC / 4) * (MT / MR);

  for (int i = tid; i < MT * 32; i += nthreads) {
    int r = i >> 5, k = (i & 31) * 4;
    int row = m0 + r;
    float4 v = make_float4(0.f, 0.f, 0.f, 0.f);
    if (row < Mrows) {
      v = *(const float4*)(A + (size_t)row * C_ + k);
      if (MODE == 1) {
        float4 v2 = *(const float4*)(A2 + (size_t)row * C_ + k);
        v.x += v2.x; v.y += v2.y; v.z += v2.z; v.w += v2.w;
      }
    }
    *(float4*)(&Alds[r][k]) = v;
  }
  __syncthreads();
  if (tid >= NTHR) return;

  int ci = tid % (NC / 4);
  int mi = tid / (NC / 4);
  int c0 = ci * 4, r0 = mi * MR;

  const float* bs;
  if (MODE == 1) bs = (c0 < 64) ? bias0 + c0 : bias1 + (c0 - 64);
  else bs = bias0 + c0;

  float acc[MR][4];
#pragma unroll
  for (int j = 0; j < MR; ++j)
#pragma unroll
    for (int cc = 0; cc < 4; ++cc) acc[j][cc] = bs[cc];

#pragma unroll 2
  for (int k4 = 0; k4 < C_; k4 += 4) {
    float bf[16];
#pragma unroll
    for (int kk = 0; kk < 4; ++kk) {
      int k = k4 + kk;
      float4 b4;
      if (MODE == 1)
        b4 = (c0 < 64) ? *(const float4*)(B0 + (size_t)k * 64 + c0)
                       : *(const float4*)(B1 + (size_t)k * 32 + (c0 - 64));
      else
        b4 = *(const float4*)(B0 + (size_t)k * NC + c0);
      bf[kk * 4 + 0] = b4.x; bf[kk * 4 + 1] = b4.y;
      bf[kk * 4 + 2] = b4.z; bf[kk * 4 + 3] = b4.w;
    }
    float af[MR * 4];
#pragma unroll
    for (int j = 0; j < MR; ++j) {
      float4 a4 = *(const float4*)(&Alds[r0 + j][k4]);
      af[j * 4 + 0] = a4.x; af[j * 4 + 1] = a4.y;
      af[j * 4 + 2] = a4.z; af[j * 4 + 3] = a4.w;
    }
#pragma unroll
    for (int j = 0; j < MR; ++j)
#pragma unroll
      for (int kk = 0; kk < 4; ++kk)
#pragma unroll
        for (int cc = 0; cc < 4; ++cc)
          acc[j][cc] = fmaf(af[j * 4 + kk], bf[kk * 4 + cc], acc[j][cc]);
  }

#pragma unroll
  for (int j = 0; j < MR; ++j) {
    int row = m0 + r0 + j;
    if (row >= Mrows) continue;
    if (MODE == 0) {
      int s = row / M_, mm = row % M_;
      int y = mm / WF_, x = mm % WF_;
      int h = c0 >> 5, d0 = c0 & 31;
      int w = __builtin_amdgcn_cvt_pk_fp8_f32(acc[j][0], acc[j][1], 0, false);
      w = __builtin_amdgcn_cvt_pk_fp8_f32(acc[j][2], acc[j][3], w, true);
      size_t hm = (size_t)s * H_ + h;
      *(int*)(out8 + (hm * M_ + mm) * 32 + d0) = w;       // copy A
      if (x > 0) {                                        // copy B
        int kp = (x - 1) >> 1, slot = 1 - (x & 1);
        *(int*)(out8 + ABYTES + ((hm * HF_ + y) * 25 + kp) * 64 +
                slot * 32 + d0) = w;
      }
    } else if (MODE == 1) {
      *(float4*)(outf + (size_t)row * 96 + c0) =
          make_float4(acc[j][0], acc[j][1], acc[j][2], acc[j][3]);
    }
  }
}

// ---------------------------------------------------------------------------
__global__ __launch_bounds__(256) void prep_kernel(
    const float* __restrict__ value, const float* __restrict__ w_val,
    const float* __restrict__ b_val, char* __restrict__ vh8,
    const float* __restrict__ query, const float* __restrict__ query_pos,
    const float* __restrict__ w_off, const float* __restrict__ b_off,
    const float* __restrict__ w_attn, const float* __restrict__ b_attn,
    float* __restrict__ OFFL) {
  __shared__ float Alds[32][132];
  int bid = blockIdx.x;
  if (bid < NB_V) {
    gemm_body<128, 32, 4, 0>(value, nullptr, w_val, nullptr, b_val, nullptr,
                             nullptr, vh8, SM_, bid * 32, threadIdx.x, 256,
                             Alds);
  } else {
    gemm_body<96, 32, 4, 1>(query, query_pos, w_off, w_attn, b_off, b_attn,
                            OFFL, nullptr, N_, (bid - NB_V) * 32, threadIdx.x,
                            256, Alds);
  }
}

// ---------------------------------------------------------------------------
// Fused deformable sampling + output projection. QB_=8 queries / 256 threads.
// Role-split gather (lane = rowsel x xsel x chalf, one dwordx4/sample) with
// a register DOUBLE-BUFFERED param pipeline: batch b+1's 8 offsets+weights
// ds_read while batch b's global loads run; sched_barrier(0) pins the order
// so the compiler cannot pressure-sink the preload back to its uses (which
// it silently did in R14 — VGPR_Count 52 proved the hoist never happened).
// ---------------------------------------------------------------------------
__global__ __launch_bounds__(256) void attn2_kernel(
    const float* __restrict__ OFFL,     // (N,96): [0:64)=off, [64:96)=logits
    const float* __restrict__ refpts,   // (S,1,N,D,2)
    const int*   __restrict__ bev_mask, // (S,1,N,D)
    const char*  __restrict__ wsbase,   // d_ws base; value data at +64 (dual)
    const float* __restrict__ query,    // (N,128)
    const float* __restrict__ w_out,    // (128,128)
    const float* __restrict__ b_out,    // (128)
    float* __restrict__ out) {          // (N,128)
  int n0 = blockIdx.x * QB_;
  int tid = threadIdx.x;

  // ---- manual LDS layout (~30 KB) ----------------------------------------
  __shared__ char smem[30656];
  int2*   sidx  = (int2*)smem;                       // [q*194+j] 12416 B
  half4h* swh   = (half4h*)(smem + 12416);           // [q*194+j] 12416 B
  float*  offp  = (float*)(smem + 24832);            // [q*64+c]  2048 B
  float*  logtp = (float*)(smem + 24832 + 2048);     // [q*32+j]  1024 B
  float*  awp   = (float*)(smem + 24832 + 3072);     // [q*32+j]  1024 B
  float*  reflp = (float*)(smem + 24832 + 4096);     // [q*48+r]  1536 B
  float*  slp   = (float*)(smem + 24832);            // [q*132+k] overlays
  int*    smaskp= (int*)(smem + 30464);              // [q*6+s]   192 B

  // ---- stage -------------------------------------------------------------
  for (int i = tid; i < QB_ * 96; i += 256) {
    int q = i / 96, c = i % 96;
    float v = OFFL[(size_t)(n0 + q) * 96 + c];
    if (c < 64) offp[q * 64 + c] = v; else logtp[q * 32 + c - 64] = v;
  }
  for (int i = tid; i < QB_ * 48; i += 256) {
    int q = i / 48, rem = i % 48;
    int s = rem >> 3, r8 = rem & 7;
    reflp[q * 48 + rem] = refpts[((size_t)s * N_ + (n0 + q)) * 8 + r8];
  }
  if (tid < QB_ * 6) {
    int q = tid / 6, s = tid % 6;
    const int* bm = bev_mask + ((size_t)s * N_ + (n0 + q)) * D_;
    smaskp[tid] = (bm[0] | bm[1] | bm[2] | bm[3]) ? 1 : 0;
  }
  __syncthreads();

  // ---- softmax over P per head -------------------------------------------
  {
    int q = tid >> 5, j = tid & 31, h = j >> 3;
    float mx = -1e30f;
#pragma unroll
    for (int p = 0; p < P_; ++p) mx = fmaxf(mx, logtp[q * 32 + h * P_ + p]);
    float sum = 0.f;
#pragma unroll
    for (int p = 0; p < P_; ++p) sum += expf(logtp[q * 32 + h * P_ + p] - mx);
    awp[q * 32 + j] = expf(logtp[q * 32 + j] - mx) / sum;
  }
  __syncthreads();

  // ---- per-sample params: j = s*32 + p*4 + h; smask folded into weights --
  for (int i = tid; i < QB_ * 192; i += 256) {
    int q = i / 192, j = i % 192;
    int s = j >> 5, w32 = j & 31, p = w32 >> 2, h = w32 & 3;
    int pd = p >> 2, dd = p & 3;
    float rx = reflp[q * 48 + s * 8 + dd * 2 + 0];
    float ry = reflp[q * 48 + s * 8 + dd * 2 + 1];
    float ox = offp[q * 64 + h * 16 + pd * 8 + dd * 2 + 0];
    float oy = offp[q * 64 + h * 16 + pd * 8 + dd * 2 + 1];
    float ix = rx * (float)WF_ + ox - 0.5f;
    float iy = ry * (float)HF_ + oy - 0.5f;
    float x0f = floorf(ix), y0f = floorf(iy);
    int x0 = (int)x0f, y0 = (int)y0f;
    float wx1 = ix - x0f, wy1 = iy - y0f;
    float wx0 = 1.f - wx1, wy0 = 1.f - wy1;
    float a = awp[q * 32 + h * P_ + p] * (float)smaskp[q * 6 + s];
    bool vx0 = (x0 >= 0) && (x0 < WF_);
    bool vx1 = (x0 + 1 >= 0) && (x0 + 1 < WF_);
    bool vy0 = (y0 >= 0) && (y0 < HF_);
    bool vy1 = (y0 + 1 >= 0) && (y0 + 1 < HF_);
    int y0c = min(max(y0, 0), HF_ - 1);
    int y1c = min(max(y0 + 1, 0), HF_ - 1);
    int hm = s * H_ + h;
    int itop, ibot;
    if (x0 >= 0 && x0 <= WF_ - 2 && !(x0 & 1)) {
      itop = (hm * M_ + y0c * WF_ + x0) * 32;        // copy A, aligned
      ibot = (hm * M_ + y1c * WF_ + x0) * 32;
    } else if (x0 >= 1 && x0 <= WF_ - 1 && (x0 & 1)) {
      int kp = (x0 - 1) >> 1;                        // copy B, aligned
      itop = ABYTES + ((hm * HF_ + y0c) * 25 + kp) * 64;
      ibot = ABYTES + ((hm * HF_ + y1c) * 25 + kp) * 64;
    } else if (x0 == -1) {
      itop = (hm * M_ + y0c * WF_) * 32 - 32;        // guard-backed
      ibot = (hm * M_ + y1c * WF_) * 32 - 32;
    } else {
      itop = ibot = 0;  // all weights 0
    }
    float w00 = (vx0 && vy0) ? wx0 * wy0 * a : 0.f;
    float w10 = (vx1 && vy0) ? wx1 * wy0 * a : 0.f;
    float w01 = (vx0 && vy1) ? wx0 * wy1 * a : 0.f;
    float w11 = (vx1 && vy1) ? wx1 * wy1 * a : 0.f;
    sidx[q * 194 + j] = make_int2(itop + 64, ibot + 64);
    // role order: [w00(x0,top), w10(x1,top), w01(x0,bot), w11(x1,bot)]
    half4h wv = {(_Float16)w00, (_Float16)w10, (_Float16)w01, (_Float16)w11};
    swh[q * 194 + j] = wv;
  }
  __syncthreads();

  // ---- gather: register double-buffered param pipeline -------------------
  {
    int q = tid >> 5, t = tid & 31, h = t >> 3, c8 = t & 7;
    int rowsel = (c8 >> 2) & 1;       // 0=top row, 1=bottom row
    int xsel   = (c8 >> 1) & 1;       // 0=x0, 1=x1
    int chalf  = c8 & 1;              // which 16 channels
    int role   = c8 >> 1;             // weight index (w00,w10,w01,w11)
    int lanebyte = xsel * 32 + chalf * 16;
    const int* sxi = (const int*)(sidx + q * 194);          // [j*2+rowsel]
    const _Float16* swq = (const _Float16*)(swh + q * 194); // [j*4+role]

    int offR[2][8];
    _Float16 wR[2][8];
    // preload batch 0 (camera s=0)
#pragma unroll
    for (int i = 0; i < 8; ++i) {
      int j = i * 4 + h;
      offR[0][i] = sxi[j * 2 + rowsel];
      wR[0][i] = swq[j * 4 + role];
    }
    __builtin_amdgcn_sched_barrier(0);

    floatx2 acc[8] = {{0.f, 0.f}, {0.f, 0.f}, {0.f, 0.f}, {0.f, 0.f},
                      {0.f, 0.f}, {0.f, 0.f}, {0.f, 0.f}, {0.f, 0.f}};
#pragma unroll
    for (int b = 0; b < 6; ++b) {
      int cur = b & 1, nxt = cur ^ 1;
      if (b < 5) {
        // preload next batch: issues ds_reads, no wait needed before the
        // current batch's global loads (their addresses are already in regs)
#pragma unroll
        for (int i = 0; i < 8; ++i) {
          int j = (b + 1) * 32 + i * 4 + h;
          offR[nxt][i] = sxi[j * 2 + rowsel];
          wR[nxt][i] = swq[j * 4 + role];
        }
      }
      __builtin_amdgcn_sched_barrier(0);
#pragma unroll
      for (int i = 0; i < 8; ++i) {
        float w = (float)wR[cur][i];
        floatx2 wv = {w, w};
        int4 tq = *(const int4*)(wsbase + (offR[cur][i] + lanebyte));
        acc[0] += __builtin_amdgcn_cvt_pk_f32_fp8(tq.x, false) * wv;
        acc[1] += __builtin_amdgcn_cvt_pk_f32_fp8(tq.x, true)  * wv;
        acc[2] += __builtin_amdgcn_cvt_pk_f32_fp8(tq.y, false) * wv;
        acc[3] += __builtin_amdgcn_cvt_pk_f32_fp8(tq.y, true)  * wv;
        acc[4] += __builtin_amdgcn_cvt_pk_f32_fp8(tq.z, false) * wv;
        acc[5] += __builtin_amdgcn_cvt_pk_f32_fp8(tq.z, true)  * wv;
        acc[6] += __builtin_amdgcn_cvt_pk_f32_fp8(tq.w, false) * wv;
        acc[7] += __builtin_amdgcn_cvt_pk_f32_fp8(tq.w, true)  * wv;
      }
      __builtin_amdgcn_sched_barrier(0);
    }

    float av[16];
#pragma unroll
    for (int k = 0; k < 8; ++k) { av[2 * k] = acc[k][0]; av[2 * k + 1] = acc[k][1]; }
    // fold x-halves (lanes differing in bit1), then rows (bit2)
#pragma unroll
    for (int k = 0; k < 16; ++k) av[k] += __shfl_xor(av[k], 2);
#pragma unroll
    for (int k = 0; k < 16; ++k) av[k] += __shfl_xor(av[k], 4);

    int cnt = smaskp[q * 6 + 0] + smaskp[q * 6 + 1] + smaskp[q * 6 + 2] +
              smaskp[q * 6 + 3] + smaskp[q * 6 + 4] + smaskp[q * 6 + 5];
    float inv = 1.f / (float)(cnt > 0 ? cnt : 1);
    if (c8 < 2) {  // lanes 0/1 hold the folded 16-ch halves of head h
      float* dst = &slp[q * 132 + h * DH_ + chalf * 16];
#pragma unroll
      for (int k = 0; k < 16; ++k) dst[k] = av[k] * inv;
    }
  }
  __syncthreads();

  // ---- tiled output projection: out = sl@w_out + b_out + query -----------
  {
    int q2 = tid >> 5, c0 = (tid & 31) * 4;
    int n = n0 + q2;
    float4 qv = *(const float4*)(query + (size_t)n * C_ + c0);
    float4 bv = *(const float4*)(b_out + c0);
    floatx2 r01 = {bv.x + qv.x, bv.y + qv.y};
    floatx2 r23 = {bv.z + qv.z, bv.w + qv.w};
#pragma unroll 4
    for (int k = 0; k < C_; ++k) {
      floatx2 a = {slp[q2 * 132 + k], slp[q2 * 132 + k]};
      float4 w4 = *(const float4*)(w_out + (size_t)k * C_ + c0);
      floatx2 w01 = {w4.x, w4.y}, w23 = {w4.z, w4.w};
      r01 += a * w01;
      r23 += a * w23;
    }
    *(float4*)(out + (size_t)n * C_ + c0) =
        make_float4(r01[0], r01[1], r23[0], r23[1]);
  }
}

// ---------------------------------------------------------------------------
extern "C" void kernel_launch(void* const* d_in, const int* in_sizes, int n_in,
                              void* d_out, int out_size, void* d_ws, size_t ws_size,
                              hipStream_t stream) {
  const float* query     = (const float*)d_in[0];
  const float* value     = (const float*)d_in[2];
  const float* query_pos = (const float*)d_in[3];
  const float* refpts    = (const float*)d_in[4];
  const int*   bev_mask  = (const int*)d_in[5];
  const float* w_off     = (const float*)d_in[6];
  const float* b_off     = (const float*)d_in[7];
  const float* w_attn    = (const float*)d_in[8];
  const float* b_attn    = (const float*)d_in[9];
  const float* w_val     = (const float*)d_in[10];
  const float* b_val     = (const float*)d_in[11];
  const float* w_out     = (const float*)d_in[12];
  const float* b_out     = (const float*)d_in[13];

  char* ws = (char*)d_ws;
  char* vh8   = ws + 64;                   // dual copies: 2*ABYTES = 2,150,400
  float* OFFL = (float*)(ws + 64 + 2 * (size_t)ABYTES + 64);   // 3,840,000 B

  prep_kernel<<<NB_V + NB_O, 256, 0, stream>>>(
      value, w_val, b_val, vh8, query, query_pos, w_off, b_off, w_attn, b_attn,
      OFFL);
  attn2_kernel<<<N_ / QB_, 256, 0, stream>>>(OFFL, refpts, bev_mask, ws,
                                             query, w_out, b_out,
                                             (float*)d_out);
}